// Round 6
// baseline (351.847 us; speedup 1.0000x reference)
//
#include <hip/hip_runtime.h>
#include <cstdint>
#include <math.h>

// Problem constants
#define Bsz 4
#define Lsz 1024
#define Dsz 256
#define Hsz 8
#define HD  2048          // H*D
#define NROWS (Bsz*Lsz)   // 4096
#define INV_TEMP 0.0625f  // 1/sqrt(256)

typedef __attribute__((ext_vector_type(8))) short bf16x8;
typedef __attribute__((ext_vector_type(4))) float f32x4;

__device__ inline unsigned short f2bf(float f) {
    union { float f; unsigned u; } x; x.f = f;
    unsigned r = x.u + 0x7fffu + ((x.u >> 16) & 1u);
    return (unsigned short)(r >> 16);
}
__device__ inline float bf2f(unsigned short u) {
    union { unsigned u; float f; } x; x.u = (unsigned)u << 16; return x.f;
}

#define GBL(p) ((const __attribute__((address_space(1))) unsigned int*)(p))
#define LDS(p) ((__attribute__((address_space(3))) unsigned int*)(p))

// Core tile body: C = alpha * A @ B^T at block offset (m0, n0).
// A [M,K] bf16 lda; Bm [N,K] bf16 ldb. BK=64, XOR-swizzled LDS staging.
// EPI: 0 = plain store; 1 = scores (clamp*mask, exp*mask, bf16); 2 = pv (scale by invs[row], bf16)
// bf16 outputs bounce through LDS for coalesced uint4 stores.
template <int TMv, int TNv, typename OutT, int EPI>
__device__ __forceinline__ void gemm_body(
    const unsigned short* __restrict__ A, const unsigned short* __restrict__ Bm,
    OutT* __restrict__ C, int K, int lda, int ldb, int ldc,
    int m0, int n0, float alpha,
    const int* __restrict__ mask, const float* __restrict__ invs,
    unsigned short* S)
{
    constexpr int WMv = TMv / 2, WNv = TNv / 2;
    constexpr int IT = TMv / 32, JT = TNv / 32;
    constexpr int APASS = TMv / 32, NPASS = (TMv + TNv) / 32;

    unsigned short* As = S;
    unsigned short* Bs = S + TMv * 64;

    const int t    = threadIdx.x;
    const int lane = t & 63;
    const int w    = t >> 6;
    const int wm   = w & 1;
    const int wn   = w >> 1;

    // staging: 32 rows per pass, 8 threads/row, 16B each; global chunk XOR-swizzled by row
    const int rA = t >> 3;
    const int ch = (((t & 7) ^ (rA & 7))) * 8;
    const unsigned short* gA = A  + (size_t)(m0 + rA) * lda + ch;
    const unsigned short* gB = Bm + (size_t)(n0 + rA) * ldb + ch;

    const int fr = lane & 15;
    const int q  = lane >> 4;

    f32x4 acc[IT][JT];
#pragma unroll
    for (int i = 0; i < IT; ++i)
#pragma unroll
        for (int j = 0; j < JT; ++j) acc[i][j] = (f32x4){0.f, 0.f, 0.f, 0.f};

    for (int k0 = 0; k0 < K; k0 += 64) {
#pragma unroll
        for (int p = 0; p < NPASS; ++p) {
            const unsigned short* src = (p < APASS)
                ? (gA + (size_t)p * 32 * lda + k0)
                : (gB + (size_t)(p - APASS) * 32 * ldb + k0);
            __builtin_amdgcn_global_load_lds(GBL(src), LDS(S + p * 2048 + t * 8), 16, 0, 0);
        }
        __syncthreads();

#pragma unroll
        for (int ks = 0; ks < 2; ++ks) {
            const int slot = ((ks * 4 + q) ^ (fr & 7)) * 8;  // de-swizzle
            bf16x8 a[IT], b[JT];
#pragma unroll
            for (int i = 0; i < IT; ++i)
                a[i] = *(const bf16x8*)(As + (wm * WMv + i * 16 + fr) * 64 + slot);
#pragma unroll
            for (int j = 0; j < JT; ++j)
                b[j] = *(const bf16x8*)(Bs + (wn * WNv + j * 16 + fr) * 64 + slot);
#pragma unroll
            for (int i = 0; i < IT; ++i)
#pragma unroll
                for (int j = 0; j < JT; ++j)
                    acc[i][j] = __builtin_amdgcn_mfma_f32_16x16x32_bf16(a[i], b[j], acc[i][j], 0, 0, 0);
        }
        __syncthreads();
    }

    // ---- epilogue ----
    constexpr bool BF16OUT = (EPI != 0) || (sizeof(OutT) == 2);
    if constexpr (BF16OUT) {
        // bounce through LDS (staging buffer is free) for coalesced stores.
        constexpr int HALVES = TMv / 64;   // 1 for TMv=64, 2 for TMv=128
        unsigned short* T = S;             // [64][TNv] bf16
#pragma unroll
        for (int hm = 0; hm < HALVES; ++hm) {
            if (HALVES == 1 || wm == hm) {
#pragma unroll
                for (int i = 0; i < IT; ++i) {
#pragma unroll
                    for (int r = 0; r < 4; ++r) {
                        const int rl = (HALVES == 1 ? wm * WMv : 0) + i * 16 + q * 4 + r;
                        const int grow = m0 + (HALVES == 1 ? 0 : hm * 64) + rl;
#pragma unroll
                        for (int j = 0; j < JT; ++j) {
                            const int col = wn * WNv + j * 16 + fr;  // tile-local
                            float vv = acc[i][j][r] * alpha;
                            if (EPI == 1) {
                                const float m = (float)mask[(size_t)grow * Lsz + (n0 + col)];
                                vv = fminf(fmaxf(vv, -15.f), 15.f) * m;
                                vv = __expf(vv) * m;
                            } else if (EPI == 2) {
                                vv *= invs[grow];
                            }
                            T[rl * TNv + col] = f2bf(vv);
                        }
                    }
                }
            }
            __syncthreads();
            // cooperative store: 64 rows x TNv bf16
            constexpr int ROWB = TNv * 2;
            constexpr int ITERS = (64 * TNv * 2) / (256 * 16);
#pragma unroll
            for (int it = 0; it < ITERS; ++it) {
                const int off = t * 16 + it * 4096;       // byte offset in T
                const int rl  = off / ROWB;
                const int ce  = (off % ROWB) / 2;         // tile-local col element
                uint4 d = *(const uint4*)((const char*)T + off);
                const int grow = m0 + (HALVES == 1 ? 0 : hm * 64) + rl;
                *(uint4*)((unsigned short*)C + (size_t)grow * ldc + (n0 + ce)) = d;
            }
            __syncthreads();
        }
    } else {
        // fp32 direct store path (fc partials)
#pragma unroll
        for (int i = 0; i < IT; ++i) {
#pragma unroll
            for (int r = 0; r < 4; ++r) {
                const int row = m0 + wm * WMv + i * 16 + q * 4 + r;
#pragma unroll
                for (int j = 0; j < JT; ++j) {
                    const int col = n0 + wn * WNv + j * 16 + fr;
                    C[(size_t)row * ldc + col] = (OutT)(acc[i][j][r] * alpha);
                }
            }
        }
    }
}

// z-batched A@B^T wrapper (2-level batch index)
template <int TMv, int TNv, typename OutT, int EPI>
__global__ __launch_bounds__(256, 2) void gemm_bt(
    const unsigned short* __restrict__ A, const unsigned short* __restrict__ Bm,
    OutT* __restrict__ C,
    int K, int lda, int ldb, int ldc, int inner,
    long long sA1, long long sA2, long long sB1, long long sB2,
    long long sC1, long long sC2, float alpha,
    const int* __restrict__ mask, long long sM2,
    const float* __restrict__ invs, long long sI1, long long sI2)
{
    __shared__ unsigned short S[(TMv + TNv) * 64];
    const int z  = blockIdx.z;
    const int i1 = z / inner;
    const int i2 = z % inner;
    A  += (size_t)i1 * sA1 + (size_t)i2 * sA2;
    Bm += (size_t)i1 * sB1 + (size_t)i2 * sB2;
    C  += (size_t)i1 * sC1 + (size_t)i2 * sC2;
    if (EPI == 1) mask += (size_t)i2 * sM2;
    if (EPI == 2) invs += (size_t)i1 * sI1 + (size_t)i2 * sI2;
    gemm_body<TMv, TNv, OutT, EPI>(A, Bm, C, K, lda, ldb, ldc,
        blockIdx.x * TMv, blockIdx.y * TNv, alpha, mask, invs, S);
}

// fused q-proj / k-proj / v-proj(transposed) in one dispatch: 1536 blocks
__global__ __launch_bounds__(256, 2) void gemm_qkv(
    const unsigned short* __restrict__ qb, const unsigned short* __restrict__ kb,
    const unsigned short* __restrict__ vb,
    const unsigned short* __restrict__ wq, const unsigned short* __restrict__ wk,
    const unsigned short* __restrict__ wv,
    unsigned short* __restrict__ qh, unsigned short* __restrict__ kh,
    unsigned short* __restrict__ vt)
{
    __shared__ unsigned short S[(64 + 256) * 64];
    const int bid = blockIdx.x;
    if (bid < 1024) {
        // jobs 0/1: qh = q @ wq^T, kh = k @ wk^T  [4096,2048], grid 64x8 each
        const int job = bid >> 9;
        const int lx  = bid & 511;
        const int m0  = (lx & 63) * 64;
        const int n0  = ((lx >> 6) & 7) * 256;
        const unsigned short* A = job ? kb : qb;
        const unsigned short* B = job ? wk : wq;
        unsigned short* C = job ? kh : qh;
        gemm_body<64, 256, unsigned short, 0>(A, B, C, Dsz, Dsz, Dsz, HD,
            m0, n0, 1.0f, nullptr, nullptr, S);
    } else {
        // job 2: vt[b] = wv @ v_b^T  [2048,1024] per b, grid 32x4x4
        const int lx = bid - 1024;
        const int m0 = (lx & 31) * 64;
        const int n0 = ((lx >> 5) & 3) * 256;
        const int b  = lx >> 7;
        gemm_body<64, 256, unsigned short, 0>(wv, vb + (size_t)b * Lsz * Dsz,
            vt + (size_t)b * HD * Lsz, Dsz, Dsz, Dsz, Lsz,
            m0, n0, 1.0f, nullptr, nullptr, S);
    }
}

// ---- fp32->bf16 cast of all GEMM inputs ----
__global__ __launch_bounds__(256) void cast_all(
    const float* __restrict__ q, const float* __restrict__ k, const float* __restrict__ v,
    const float* __restrict__ wq, const float* __restrict__ wk, const float* __restrict__ wv,
    const float* __restrict__ fw,
    unsigned short* __restrict__ qb, unsigned short* __restrict__ kb, unsigned short* __restrict__ vb,
    unsigned short* __restrict__ wqb, unsigned short* __restrict__ wkb, unsigned short* __restrict__ wvb,
    unsigned short* __restrict__ fwb)
{
    const int gid = blockIdx.x * 256 + threadIdx.x;
    const int NQ = 262144;   // 1048576/4
    const int NW = 131072;   // 524288/4
    const float* src; unsigned short* dst; int off;
    if      (gid < NQ)            { src = q;  dst = qb;  off = gid; }
    else if (gid < 2 * NQ)        { src = k;  dst = kb;  off = gid - NQ; }
    else if (gid < 3 * NQ)        { src = v;  dst = vb;  off = gid - 2 * NQ; }
    else if (gid < 3 * NQ + NW)   { src = wq; dst = wqb; off = gid - 3 * NQ; }
    else if (gid < 3 * NQ + 2*NW) { src = wk; dst = wkb; off = gid - 3 * NQ - NW; }
    else if (gid < 3 * NQ + 3*NW) { src = wv; dst = wvb; off = gid - 3 * NQ - 2 * NW; }
    else                          { src = fw; dst = fwb; off = gid - 3 * NQ - 3 * NW; }
    float4 f = ((const float4*)src)[off];
    ushort4 o;
    o.x = f2bf(f.x); o.y = f2bf(f.y); o.z = f2bf(f.z); o.w = f2bf(f.w);
    ((ushort4*)dst)[off] = o;
}

// ---- normalize: wave per row. read e bf16, write fp32 attn + invsum ----
__global__ __launch_bounds__(256) void norm_kernel(const unsigned short* __restrict__ e,
                                                   float* __restrict__ attn,
                                                   float* __restrict__ invsum)
{
    const int r    = blockIdx.x * 4 + (threadIdx.x >> 6);
    const int lane = threadIdx.x & 63;
    const unsigned short* rowp = e + (size_t)r * Lsz + lane * 16;

    union { uint4 v[2]; unsigned short u[16]; } buf;
    buf.v[0] = *(const uint4*)rowp;
    buf.v[1] = *(const uint4*)(rowp + 8);

    float f[16];
    float s = 0.f;
#pragma unroll
    for (int i = 0; i < 16; ++i) { f[i] = bf2f(buf.u[i]); s += f[i]; }
#pragma unroll
    for (int o = 1; o <= 32; o <<= 1) s += __shfl_xor(s, o, 64);
    const float inv = 1.0f / (s + 1e-6f);

    float* op = attn + (size_t)r * Lsz + lane * 16;
#pragma unroll
    for (int c = 0; c < 4; ++c) {
        float4 o4;
        o4.x = f[c * 4 + 0] * inv; o4.y = f[c * 4 + 1] * inv;
        o4.z = f[c * 4 + 2] * inv; o4.w = f[c * 4 + 3] * inv;
        *(float4*)(op + c * 4) = o4;
    }
    if (lane == 0) invsum[r] = inv;
}

// ---- sum 4 fc split-K partials + fc_b + residual -> LayerNorm -> out ----
__global__ __launch_bounds__(256) void ln_kernel(const float* __restrict__ gout,
                                                 const float* __restrict__ qin,
                                                 const float* __restrict__ fc_b,
                                                 const float* __restrict__ ln_g,
                                                 const float* __restrict__ ln_b,
                                                 float* __restrict__ out)
{
    const int row = blockIdx.x;
    const int t = threadIdx.x;
    const size_t idx = (size_t)row * Dsz + t;
    const size_t P = (size_t)NROWS * Dsz;
    const float val = gout[idx] + gout[idx + P] + gout[idx + 2 * P] + gout[idx + 3 * P]
                    + fc_b[t] + qin[idx];

    __shared__ float red[4];
    float s = val;
#pragma unroll
    for (int o = 32; o > 0; o >>= 1) s += __shfl_down(s, o, 64);
    const int lane = t & 63, w = t >> 6;
    if (lane == 0) red[w] = s;
    __syncthreads();
    const float mu = (red[0] + red[1] + red[2] + red[3]) * (1.0f / Dsz);
    __syncthreads();

    float d = val - mu;
    float s2 = d * d;
#pragma unroll
    for (int o = 32; o > 0; o >>= 1) s2 += __shfl_down(s2, o, 64);
    if (lane == 0) red[w] = s2;
    __syncthreads();
    const float var = (red[0] + red[1] + red[2] + red[3]) * (1.0f / Dsz);

    out[idx] = d * rsqrtf(var + 1e-5f) * ln_g[t] + ln_b[t];
}

extern "C" void kernel_launch(void* const* d_in, const int* in_sizes, int n_in,
                              void* d_out, int out_size, void* d_ws, size_t ws_size,
                              hipStream_t stream)
{
    const float* q    = (const float*)d_in[0];
    const int*   mask = (const int*)d_in[1];
    const float* k    = (const float*)d_in[2];
    const float* v    = (const float*)d_in[3];
    const float* w_qs = (const float*)d_in[4];
    const float* w_ks = (const float*)d_in[5];
    const float* w_vs = (const float*)d_in[6];
    const float* fc_w = (const float*)d_in[7];
    const float* fc_b = (const float*)d_in[8];
    const float* ln_g = (const float*)d_in[9];
    const float* ln_b = (const float*)d_in[10];

    float* out  = (float*)d_out;                       // [B,L,D]
    float* attn = (float*)d_out + (size_t)NROWS * Dsz; // [H*B,L,L] fp32 normalized

    // Workspace layout (ushort units)
    unsigned short* wsu = (unsigned short*)d_ws;
    unsigned short* qh     = wsu;                                  // [4096,2048]
    unsigned short* kh     = qh + (size_t)NROWS * HD;              // [4096,2048]
    unsigned short* q_bf   = kh + (size_t)NROWS * HD;              // [4096,256] x3
    unsigned short* k_bf   = q_bf + (size_t)NROWS * Dsz;
    unsigned short* v_bf   = k_bf + (size_t)NROWS * Dsz;
    unsigned short* wq_bf  = v_bf + (size_t)NROWS * Dsz;           // [2048,256] x3
    unsigned short* wk_bf  = wq_bf + (size_t)HD * Dsz;
    unsigned short* wv_bf  = wk_bf + (size_t)HD * Dsz;
    unsigned short* vt     = wv_bf + (size_t)HD * Dsz;             // [B,2048,1024]
    unsigned short* attn_e = vt + (size_t)Bsz * HD * Lsz;          // [32,1024,1024] unnormalized e
    unsigned short* attnv  = attn_e + (size_t)32 * Lsz * Lsz;      // [4096,2048]
    unsigned short* fcw_bf = attnv + (size_t)NROWS * HD;           // [256,2048]
    float*          invsum = (float*)(fcw_bf + (size_t)Dsz * HD);  // [32768]
    float*          fcout  = invsum + 32768;                       // [4,4096,256] split-K partials

    dim3 blk(256);

    // 0) cast everything to bf16
    cast_all<<<dim3(5120), blk, 0, stream>>>(q, k, v, w_qs, w_ks, w_vs, fc_w,
                                             q_bf, k_bf, v_bf, wq_bf, wk_bf, wv_bf, fcw_bf);

    // 1) fused q/k/v projections: qh, kh [4096,2048]; vt [B,2048,1024]
    gemm_qkv<<<dim3(1536), blk, 0, stream>>>(q_bf, k_bf, v_bf, wq_bf, wk_bf, wv_bf,
                                             qh, kh, vt);

    // 2) scores + clamp/mask/exp: attn_e[z] = exp(clamp(qh kh^T /16)*m)*m (bf16). 128x256, grid 8x4x32.
    {
        dim3 grid(Lsz / 128, Lsz / 256, Hsz * Bsz);
        gemm_bt<128, 256, unsigned short, 1><<<grid, blk, 0, stream>>>(qh, kh, attn_e,
            Dsz, HD, HD, Lsz, Bsz,
            Dsz, (long long)Lsz * HD, Dsz, (long long)Lsz * HD,
            (long long)Bsz * Lsz * Lsz, (long long)Lsz * Lsz,
            INV_TEMP, mask, (long long)Lsz * Lsz, nullptr, 0, 0);
    }

    // 3) normalize: fp32 attn output + per-row 1/(sum+eps). Wave per row.
    norm_kernel<<<dim3(32 * Lsz / 4), blk, 0, stream>>>(attn_e, attn, invsum);

    // 4) pv: attnv = (e @ vt^T) * inv[row]. 64x256 full-N tile, grid 16x1x32.
    {
        dim3 grid(Lsz / 64, Dsz / 256, Hsz * Bsz);
        gemm_bt<64, 256, unsigned short, 2><<<grid, blk, 0, stream>>>(attn_e, vt, attnv,
            Lsz, Lsz, Lsz, HD, Bsz,
            (long long)Bsz * Lsz * Lsz, (long long)Lsz * Lsz,
            (long long)Dsz * Lsz, (long long)HD * Lsz,
            Dsz, (long long)Lsz * HD,
            1.0f, nullptr, 0, invsum, (long long)Bsz * Lsz, (long long)Lsz);
    }

    // 5) fc split-K x4: fcout[p] = attnv[:, p*512:+512] @ fc_w[:, p*512:+512]^T. 64x256, grid 64x1x4.
    {
        dim3 grid(NROWS / 64, Dsz / 256, 4);
        gemm_bt<64, 256, float, 0><<<grid, blk, 0, stream>>>(attnv, fcw_bf, fcout,
            512, HD, HD, Dsz, 4,
            0, 512, 0, 512, 0, (long long)NROWS * Dsz,
            1.0f, nullptr, 0, nullptr, 0, 0);
    }

    // 6) sum partials + bias + residual + LayerNorm
    ln_kernel<<<dim3(NROWS), blk, 0, stream>>>(fcout, q, fc_b, ln_g, ln_b, out);
}